// Round 5
// baseline (1636.442 us; speedup 1.0000x reference)
//
#include <hip/hip_runtime.h>

// RNN_16492674416646: h_t = tanh(x_t W_ih^T + b_ih + b_hh + h_{t-1} W_hh^T),
// out_t = h_t W_out^T + b_out. T=2048, B=128, IN=2, H=200, OUT=1, fp32.
//
// One block per batch element. 576 threads = 9 waves:
//   waves 0..7 : k-slice s (25 wide); lane g<50 owns rows 4g..4g+3.
//                100 W_hh floats/thread held in VGPRs, re-pinned with
//                asm volatile tied-operand statements EVERY iteration ->
//                loop-carried opaque values the compiler cannot
//                rematerialize from memory (R2/R3 failure: VGPR=40/64,
//                per-step W_hh re-fetch). 4 asm stmts x 25 operands
//                (vs R4's 100 stmts -- suspected compile blowup).
//   wave 8     : dedicated head wave; runs between barrier2 and next
//                barrier1, hidden under waves 0..7's phase 1.
// h broadcast: 1 cooperative ds_read_b32/wave + 25 v_readlane -> SGPR FMA.
// Phase 2 balanced: wave s, lanes 0..24 own j = 25s+lane.

static constexpr int T = 2048;
static constexpr int B = 128;
static constexpr int H = 200;
static constexpr int KS = 25;     // k-slice width per compute wave
static constexpr int S  = 8;      // compute waves = k-slices
static constexpr int R  = 4;      // rows per lane
static constexpr int NTHR = 576;  // 9 waves

#define PIN25(w) asm volatile("" : \
    "+v"(w[0]),  "+v"(w[1]),  "+v"(w[2]),  "+v"(w[3]),  "+v"(w[4]),  \
    "+v"(w[5]),  "+v"(w[6]),  "+v"(w[7]),  "+v"(w[8]),  "+v"(w[9]),  \
    "+v"(w[10]), "+v"(w[11]), "+v"(w[12]), "+v"(w[13]), "+v"(w[14]), \
    "+v"(w[15]), "+v"(w[16]), "+v"(w[17]), "+v"(w[18]), "+v"(w[19]), \
    "+v"(w[20]), "+v"(w[21]), "+v"(w[22]), "+v"(w[23]), "+v"(w[24]))

__global__ __launch_bounds__(NTHR, 2)
void rnn_fused(const float* __restrict__ x,     // [T,B,2]
               const float* __restrict__ W_ih,  // [H,2]
               const float* __restrict__ W_hh,  // [H,H]
               const float* __restrict__ b_ih,  // [H]
               const float* __restrict__ b_hh,  // [H]
               const float* __restrict__ W_out, // [1,H]
               const float* __restrict__ b_out, // [1]
               float* __restrict__ out)         // [T,B]
{
    const int b    = blockIdx.x;
    const int tid  = threadIdx.x;
    const int s    = tid >> 6;          // wave id
    const int lane = tid & 63;
    const bool cw  = (s < S);           // compute wave?
    const bool rowact = cw && (lane < 50);
    const int g    = (lane < 50) ? lane : 49;   // clamp for safe one-time loads
    const int j0   = R * g;
    const int k0   = KS * (cw ? s : 0);

    __shared__ float hbuf[H];           // current hidden state
    __shared__ float part[S][H];        // per-slice partials
    __shared__ float xs[2 * T];         // this block's x column (16 KB)

    // --- one-time: weights into registers (waves 0..7) ---
    float w0[KS], w1[KS], w2[KS], w3[KS];
    if (cw) {
#pragma unroll
        for (int i = 0; i < KS; ++i) {
            w0[i] = W_hh[(j0 + 0) * H + k0 + i];
            w1[i] = W_hh[(j0 + 1) * H + k0 + i];
            w2[i] = W_hh[(j0 + 2) * H + k0 + i];
            w3[i] = W_hh[(j0 + 3) * H + k0 + i];
        }
    } else {
#pragma unroll
        for (int i = 0; i < KS; ++i) { w0[i]=w1[i]=w2[i]=w3[i]=0.f; }
    }

    // --- one-time: stage x[:, b, :] into LDS ---
    for (int idx = tid; idx < T; idx += NTHR) {
        const float2 v = *(const float2*)(x + (size_t)idx * (B * 2) + 2 * b);
        xs[2 * idx + 0] = v.x;
        xs[2 * idx + 1] = v.y;
    }

    // --- one-time: phase-2 constants. Thread (s,lane<25) owns j = 25s+lane.
    const int jp = 25 * (cw ? s : 0) + ((lane < 25) ? lane : 24);
    float wih0 = 0.f, wih1 = 0.f, bias = 0.f;
    if (cw) {
        wih0 = W_ih[jp * 2 + 0];
        wih1 = W_ih[jp * 2 + 1];
        bias = b_ih[jp] + b_hh[jp];
    }

    // --- one-time: head-wave constants (wave 8) ---
    float wo0 = 0.f, wo1 = 0.f, wo2 = 0.f, wo3 = 0.f, bo = 0.f;
    if (!cw) {
        wo0 = W_out[lane];
        wo1 = W_out[64 + lane];
        wo2 = W_out[128 + lane];
        wo3 = (lane < H - 192) ? W_out[192 + lane] : 0.f;
        bo  = b_out[0];
    }

    if (tid < H) hbuf[tid] = 0.f;       // h_0 = 0
    __syncthreads();

    float* op = out + b;

    for (int t = 0; t < T; ++t) {
        // re-pin weights: loop-carried opaque register values (see header)
        PIN25(w0); PIN25(w1); PIN25(w2); PIN25(w3);

        // xs is static -> read at loop top, off the phase-2 critical path
        const float x0 = xs[2 * t + 0];
        const float x1 = xs[2 * t + 1];

        // --- phase 1 (waves 0..7): h slice -> SGPR broadcast -> FMA ---
        if (cw) {
            const int hidx = (lane < KS) ? lane : 0;
            const float hval = hbuf[k0 + hidx];     // ONE ds_read_b32 / wave

            float a0 = 0.f, a1 = 0.f, a2 = 0.f, a3 = 0.f;
#pragma unroll
            for (int i = 0; i < KS; ++i) {
                const float hs = __int_as_float(
                    __builtin_amdgcn_readlane(__float_as_int(hval), i));
                a0 = fmaf(w0[i], hs, a0);
                a1 = fmaf(w1[i], hs, a1);
                a2 = fmaf(w2[i], hs, a2);
                a3 = fmaf(w3[i], hs, a3);
            }
            if (rowact) {
                float4 v; v.x = a0; v.y = a1; v.z = a2; v.w = a3;
                *(float4*)&part[s][j0] = v;         // conflict-free b128
            }
        }
        __syncthreads();

        // --- phase 2 (8 compute waves, lanes 0..24): j = 25s+lane ---
        if (cw && lane < 25) {
            const float p01 = part[0][jp] + part[1][jp];
            const float p23 = part[2][jp] + part[3][jp];
            const float p45 = part[4][jp] + part[5][jp];
            const float p67 = part[6][jp] + part[7][jp];
            const float sum = (p01 + p23) + (p45 + p67);
            const float pre = sum + fmaf(x0, wih0, fmaf(x1, wih1, bias));
            // tanh(x) = 1 - 2/(e^{2x}+1); saturates correctly at +-inf
            const float e  = __expf(2.f * pre);
            hbuf[jp] = 1.f - 2.f / (e + 1.f);
        }
        __syncthreads();

        // --- head (wave 8): hidden under waves 0..7's next phase 1 ---
        if (!cw) {
            const int l3 = (lane < H - 192) ? lane : 0;
            float v = hbuf[lane] * wo0 + hbuf[64 + lane] * wo1
                    + hbuf[128 + lane] * wo2 + hbuf[192 + l3] * wo3;
#pragma unroll
            for (int off = 32; off > 0; off >>= 1)
                v += __shfl_down(v, off, 64);
            if (lane == 0) op[(size_t)t * B] = v + bo;
        }
    }
}

extern "C" void kernel_launch(void* const* d_in, const int* in_sizes, int n_in,
                              void* d_out, int out_size, void* d_ws, size_t ws_size,
                              hipStream_t stream) {
    const float* x     = (const float*)d_in[0];
    const float* W_ih  = (const float*)d_in[1];
    const float* W_hh  = (const float*)d_in[2];
    const float* b_ih  = (const float*)d_in[3];
    const float* b_hh  = (const float*)d_in[4];
    const float* W_out = (const float*)d_in[5];
    const float* b_out = (const float*)d_in[6];
    float* out = (float*)d_out;

    rnn_fused<<<B, NTHR, 0, stream>>>(x, W_ih, W_hh, b_ih, b_hh, W_out, b_out, out);
}

// Round 7
// 1421.494 us; speedup vs baseline: 1.1512x; 1.1512x over previous
//
#include <hip/hip_runtime.h>

// RNN_16492674416646: h_t = tanh(x_t W_ih^T + b_ih + b_hh + h_{t-1} W_hh^T),
// out_t = h_t W_out^T + b_out. T=2048, B=128, IN=2, H=200, OUT=1, fp32.
//
// One block per batch element (128 blocks, 512 threads = 8 waves).
// Wave s owns k-slice [25s,25s+25); lane g<50 owns rows 4g..4g+3.
//
// Register-residency fix (R2/R3/R5 showed VGPR 40-68 => weight arrays
// stayed allocas/scratch; R6's float4 asm pins don't compile -- tied
// vector asm operands unsupported): 100 weights are 100 individually
// NAMED SCALAR float SSA variables (macro-generated), pinned in-loop by
// 4 asm stmts x 25 scalar tied operands (the form that compiled in R5).
//
// Head: h states go to an 8-deep LDS ring; every 8 steps wave s computes
// out[t-7+s] = ring[s].W_out -- amortized off the critical path.
// Safety: head reads of slot s finish before that wave passes the next
// barrier1; slot s is rewritten only after barrier1 (phase 2).

static constexpr int T = 2048;
static constexpr int B = 128;
static constexpr int H = 200;
static constexpr int KS = 25;     // k-slice width per wave
static constexpr int S  = 8;      // waves = slices
static constexpr int NTHR = 512;

#define WLIST(X) X(0) X(1) X(2) X(3) X(4) X(5) X(6) X(7) X(8) X(9) \
    X(10) X(11) X(12) X(13) X(14) X(15) X(16) X(17) X(18) X(19) \
    X(20) X(21) X(22) X(23) X(24)

#define PINROW(r) asm volatile("" : \
    "+v"(w##r##_0),  "+v"(w##r##_1),  "+v"(w##r##_2),  "+v"(w##r##_3),  \
    "+v"(w##r##_4),  "+v"(w##r##_5),  "+v"(w##r##_6),  "+v"(w##r##_7),  \
    "+v"(w##r##_8),  "+v"(w##r##_9),  "+v"(w##r##_10), "+v"(w##r##_11), \
    "+v"(w##r##_12), "+v"(w##r##_13), "+v"(w##r##_14), "+v"(w##r##_15), \
    "+v"(w##r##_16), "+v"(w##r##_17), "+v"(w##r##_18), "+v"(w##r##_19), \
    "+v"(w##r##_20), "+v"(w##r##_21), "+v"(w##r##_22), "+v"(w##r##_23), \
    "+v"(w##r##_24))

__global__ __launch_bounds__(NTHR, 2)
void rnn_fused(const float* __restrict__ x,     // [T,B,2]
               const float* __restrict__ W_ih,  // [H,2]
               const float* __restrict__ W_hh,  // [H,H]
               const float* __restrict__ b_ih,  // [H]
               const float* __restrict__ b_hh,  // [H]
               const float* __restrict__ W_out, // [1,H]
               const float* __restrict__ b_out, // [1]
               float* __restrict__ out)         // [T,B]
{
    const int b    = blockIdx.x;
    const int tid  = threadIdx.x;
    const int s    = tid >> 6;          // wave id = k-slice id
    const int lane = tid & 63;
    const bool rowact = (lane < 50);
    const int g    = rowact ? lane : 49;   // clamp: harmless dup work
    const int j0   = 4 * g;
    const int k0   = KS * s;

    __shared__ __align__(16) float ring[8][H];   // h history, slot = t&7
    __shared__ __align__(16) float part[S][H];   // per-slice partials
    __shared__ float xs[2 * T];                  // x column (16 KB)

    // --- one-time: 100 weights as NAMED SCALAR SSA values ---
    const float* r0 = W_hh + (j0 + 0) * H + k0;
    const float* r1 = W_hh + (j0 + 1) * H + k0;
    const float* r2 = W_hh + (j0 + 2) * H + k0;
    const float* r3 = W_hh + (j0 + 3) * H + k0;
#define DECLW(i) float w0_##i = r0[i]; float w1_##i = r1[i]; \
                 float w2_##i = r2[i]; float w3_##i = r3[i];
    WLIST(DECLW)
#undef DECLW

    // --- one-time: stage x[:, b, :] into LDS ---
    for (int idx = tid; idx < T; idx += NTHR) {
        const float2 v = *(const float2*)(x + (size_t)idx * (B * 2) + 2 * b);
        xs[2 * idx + 0] = v.x;
        xs[2 * idx + 1] = v.y;
    }

    // --- one-time: phase-2 constants; thread (s, lane<25) owns jp=25s+lane
    const int jp = 25 * s + ((lane < 25) ? lane : 24);
    const float wih0 = W_ih[jp * 2 + 0];
    const float wih1 = W_ih[jp * 2 + 1];
    const float bias = b_ih[jp] + b_hh[jp];

    // --- one-time: head constants (used every 8th step) ---
    const float wo0 = W_out[lane];
    const float wo1 = W_out[64 + lane];
    const float wo2 = W_out[128 + lane];
    const float wo3 = (lane < H - 192) ? W_out[192 + lane] : 0.f;
    const float bo  = b_out[0];

    if (tid < H) ring[7][tid] = 0.f;    // h_0 = 0 (step 0 reads slot 7)
    __syncthreads();

    float* op = out + b;

    for (int t = 0; t < T; ++t) {
        // pin weights: loop-carried opaque scalar SSA values (no remat)
        PINROW(0); PINROW(1); PINROW(2); PINROW(3);

        const float x0 = xs[2 * t + 0];
        const float x1 = xs[2 * t + 1];

        // --- phase 1: h slice (1 ds_read_b32/wave) -> SGPR -> FMA ---
        const int hidx = (lane < KS) ? lane : 0;
        const float hval = ring[(t + 7) & 7][k0 + hidx];

        float a0 = 0.f, a1 = 0.f, a2 = 0.f, a3 = 0.f;
#define FMASTEP(i) { \
        const float hs_ = __int_as_float( \
            __builtin_amdgcn_readlane(__float_as_int(hval), i)); \
        a0 = fmaf(w0_##i, hs_, a0); \
        a1 = fmaf(w1_##i, hs_, a1); \
        a2 = fmaf(w2_##i, hs_, a2); \
        a3 = fmaf(w3_##i, hs_, a3); }
        WLIST(FMASTEP)
#undef FMASTEP

        if (rowact) {
            float4 v; v.x = a0; v.y = a1; v.z = a2; v.w = a3;
            *(float4*)&part[s][j0] = v;             // conflict-free b128
        }
        __syncthreads();

        // --- phase 2: 8 waves x 25 lanes, j = 25s+lane ---
        if (lane < 25) {
            const float p01 = part[0][jp] + part[1][jp];
            const float p23 = part[2][jp] + part[3][jp];
            const float p45 = part[4][jp] + part[5][jp];
            const float p67 = part[6][jp] + part[7][jp];
            const float sum = (p01 + p23) + (p45 + p67);
            const float pre = sum + fmaf(x0, wih0, fmaf(x1, wih1, bias));
            // tanh(x) = 1 - 2/(e^{2x}+1); saturates correctly at +-inf
            const float e = __expf(2.f * pre);
            ring[t & 7][jp] = 1.f - 2.f / (e + 1.f);
        }
        __syncthreads();

        // --- head, every 8 steps: wave s -> out[t-7+s] = ring[s].W_out ---
        if ((t & 7) == 7) {
            const int l3 = (lane < H - 192) ? lane : 0;
            float v = ring[s][lane] * wo0 + ring[s][64 + lane] * wo1
                    + ring[s][128 + lane] * wo2 + ring[s][192 + l3] * wo3;
#pragma unroll
            for (int off = 32; off > 0; off >>= 1)
                v += __shfl_down(v, off, 64);
            if (lane == 0) op[(size_t)(t - 7 + s) * B] = v + bo;
        }
    }
}

extern "C" void kernel_launch(void* const* d_in, const int* in_sizes, int n_in,
                              void* d_out, int out_size, void* d_ws, size_t ws_size,
                              hipStream_t stream) {
    const float* x     = (const float*)d_in[0];
    const float* W_ih  = (const float*)d_in[1];
    const float* W_hh  = (const float*)d_in[2];
    const float* b_ih  = (const float*)d_in[3];
    const float* b_hh  = (const float*)d_in[4];
    const float* W_out = (const float*)d_in[5];
    const float* b_out = (const float*)d_in[6];
    float* out = (float*)d_out;

    rnn_fused<<<B, NTHR, 0, stream>>>(x, W_ih, W_hh, b_ih, b_hh, W_out, b_out, out);
}